// Round 9
// baseline (171.615 us; speedup 1.0000x reference)
//
#include <hip/hip_runtime.h>

// KMeans soft-assignment via bf16 hi/lo split MFMA (3 passes), fused softmax.
// logits = (2*x.c - ||c||^2)/T, T=0.1; ||x||^2 cancels in softmax.
// R9: BM=128, wn-split waves (32 rows x 256 cols: 3 MFMA per B ds_read);
// A read direct from global (no A LDS, no staging regs); single-buffer B
// staging with SHORT-LIVED registers (no live-across-MFMA buffer -> no spill,
// which was R8's 102 MB phantom WRITE).
// x: [32768,256] f32, c: [512,256] f32, out: [32768,512] f32
#define NROWS 32768
#define KC 512
#define DDIM 256
#define BM 128
#define BK 32
#define KCH (DDIM / BK)        // 8 k-chunks
#define CHUNK_USH (KC * BK)    // 16384 ushorts = 32 KB per chunk table

typedef __attribute__((ext_vector_type(8))) short bf16x8;
typedef __attribute__((ext_vector_type(4))) float f32x4;

union U8 { unsigned short u[8]; bf16x8 v; };

__device__ __forceinline__ unsigned short f2bf(float f) {   // RNE f32->bf16
    union { float f; unsigned int u; } a; a.f = f;
    unsigned int r = a.u + 0x7fffu + ((a.u >> 16) & 1u);
    return (unsigned short)(r >> 16);
}
__device__ __forceinline__ float bf2f(unsigned short h) {
    union { unsigned int u; float f; } a; a.u = ((unsigned int)h) << 16;
    return a.f;
}

// ---- prep: c -> chunk-major, LDS-swizzle-baked bf16 hi/lo + csq10 ----
// octet (col n, quad q) at chunk offset (n*4 + (q ^ ((n>>1)&3)))*8 ushorts
__global__ __launch_bounds__(64) void prep_c(const float* __restrict__ c,
                                             unsigned short* __restrict__ bhi,
                                             unsigned short* __restrict__ blo,
                                             float* __restrict__ csq10) {
    const int n = blockIdx.x, lane = threadIdx.x;
    const int d0 = lane * 4;
    float4 v = ((const float4*)(c + (size_t)n * DDIM))[lane];
    float vv[4] = {v.x, v.y, v.z, v.w};
    unsigned short hh[4], ll[4];
    float ssq = 0.f;
    #pragma unroll
    for (int i = 0; i < 4; ++i) {
        ssq += vv[i] * vv[i];
        hh[i] = f2bf(vv[i]);
        ll[i] = f2bf(vv[i] - bf2f(hh[i]));
    }
    #pragma unroll
    for (int off = 32; off; off >>= 1) ssq += __shfl_xor(ssq, off);
    if (lane == 0) csq10[n] = 10.f * ssq;
    const int ks = d0 >> 5;
    const int q  = (d0 >> 3) & 3;
    const int s  = q ^ ((n >> 1) & 3);
    const size_t dst = (size_t)ks * CHUNK_USH + (n * 4 + s) * 8 + (d0 & 7);
    *(ushort4*)(bhi + dst) = make_ushort4(hh[0], hh[1], hh[2], hh[3]);
    *(ushort4*)(blo + dst) = make_ushort4(ll[0], ll[1], ll[2], ll[3]);
}

// ---- main: 256 blocks x 512 threads (8 waves = 4 M-groups x 2 N-halves) ----
// wave (wm,wn): rows wm*32 + mt*16 (mt=0,1), cols wn*256 .. +255
union SmemU {
    struct { unsigned short Bh[CHUNK_USH], Bl[CHUNK_USH]; } k;  // 64 KB
    float lbuf[32 * 516];                                       // 66 KB overlay
};

__global__ __launch_bounds__(512, 2) void kmeans_mfma(
    const float* __restrict__ x, const unsigned short* __restrict__ bhi,
    const unsigned short* __restrict__ blo, const float* __restrict__ csq10,
    float* __restrict__ out) {
    __shared__ __align__(16) SmemU sm;
    __shared__ float red[2][2][BM];   // 4 KB (separate from union)

    const int tid  = threadIdx.x;
    const int w    = tid >> 6, lane = tid & 63;
    const int wm   = w >> 1, wn = w & 1;
    const int cc   = lane & 15, q = lane >> 4;
    const int row0 = blockIdx.x * BM;

    f32x4 acc[2][16];
    #pragma unroll
    for (int mt = 0; mt < 2; ++mt)
        #pragma unroll
        for (int t = 0; t < 16; ++t) acc[mt][t] = (f32x4){0.f, 0.f, 0.f, 0.f};

    // A: lane owns rows (row0 + wm*32 + mt*16 + cc), k-octet q*8 per chunk
    const float* xA0 = x + (size_t)(row0 + wm * 32 + cc) * DDIM + q * 8;
    const float* xA1 = xA0 + (size_t)16 * DDIM;
    // B fragment offset within staged chunk
    const int sF = q ^ ((cc >> 1) & 3);
    const int bF = (4 * cc + sF) * 8;       // + (wn*16+t)*512

    for (int ks = 0; ks < KCH; ++ks) {
        const int k0 = ks * BK;
        // B staging: short-lived batched loads (die before MFMA phase)
        uint4 th[4], tl[4];
        {
            const unsigned short* hb = bhi + (size_t)ks * CHUNK_USH;
            const unsigned short* lb = blo + (size_t)ks * CHUNK_USH;
            #pragma unroll
            for (int j = 0; j < 4; ++j) {
                const int slot = j * 512 + tid;
                th[j] = *(const uint4*)(hb + slot * 8);
                tl[j] = *(const uint4*)(lb + slot * 8);
            }
        }
        // A loads for this chunk (latency hides under barrier + staging)
        float4 a00 = *(const float4*)(xA0 + k0);
        float4 a01 = *(const float4*)(xA0 + k0 + 4);
        float4 a10 = *(const float4*)(xA1 + k0);
        float4 a11 = *(const float4*)(xA1 + k0 + 4);
        __syncthreads();   // previous MFMA phase done; safe to overwrite B
        #pragma unroll
        for (int j = 0; j < 4; ++j) {
            const int slot = j * 512 + tid;
            *(uint4*)&sm.k.Bh[slot * 8] = th[j];
            *(uint4*)&sm.k.Bl[slot * 8] = tl[j];
        }
        // convert A to hi/lo bf16 fragments
        bf16x8 ah[2], al[2];
        {
            float v0[8] = {a00.x, a00.y, a00.z, a00.w, a01.x, a01.y, a01.z, a01.w};
            float v1[8] = {a10.x, a10.y, a10.z, a10.w, a11.x, a11.y, a11.z, a11.w};
            U8 H0, L0, H1, L1;
            #pragma unroll
            for (int i = 0; i < 8; ++i) {
                H0.u[i] = f2bf(v0[i]); L0.u[i] = f2bf(v0[i] - bf2f(H0.u[i]));
                H1.u[i] = f2bf(v1[i]); L1.u[i] = f2bf(v1[i] - bf2f(H1.u[i]));
            }
            ah[0] = H0.v; al[0] = L0.v; ah[1] = H1.v; al[1] = L1.v;
        }
        __syncthreads();   // staged B visible
        #pragma unroll
        for (int t = 0; t < 16; ++t) {
            const int bo = (wn * 16 + t) * 512 + bF;
            bf16x8 bh = *(const bf16x8*)&sm.k.Bh[bo];
            bf16x8 bl = *(const bf16x8*)&sm.k.Bl[bo];
            #pragma unroll
            for (int mt = 0; mt < 2; ++mt) {
                acc[mt][t] = __builtin_amdgcn_mfma_f32_16x16x32_bf16(ah[mt], bh, acc[mt][t], 0, 0, 0);
                acc[mt][t] = __builtin_amdgcn_mfma_f32_16x16x32_bf16(ah[mt], bl, acc[mt][t], 0, 0, 0);
                acc[mt][t] = __builtin_amdgcn_mfma_f32_16x16x32_bf16(al[mt], bh, acc[mt][t], 0, 0, 0);
            }
        }
    }

    // ---- softmax stats: reduce over t, then cc-lanes, then wn pair via LDS ----
    float csqv[16];
    #pragma unroll
    for (int t = 0; t < 16; ++t) csqv[t] = csq10[wn * 256 + t * 16 + cc];
    const int rb = wm * 32 + q * 4;   // + mt*16 + g
    float M[2][4], I[2][4];
    #pragma unroll
    for (int mt = 0; mt < 2; ++mt)
        #pragma unroll
        for (int g = 0; g < 4; ++g) {
            float pm = -1e30f;
            #pragma unroll
            for (int t = 0; t < 16; ++t) pm = fmaxf(pm, 20.f * acc[mt][t][g] - csqv[t]);
            #pragma unroll
            for (int off = 1; off < 16; off <<= 1) pm = fmaxf(pm, __shfl_xor(pm, off));
            if (cc == 0) red[0][wn][rb + mt * 16 + g] = pm;
            M[mt][g] = pm;
        }
    __syncthreads();
    #pragma unroll
    for (int mt = 0; mt < 2; ++mt)
        #pragma unroll
        for (int g = 0; g < 4; ++g) {
            M[mt][g] = fmaxf(M[mt][g], red[0][1 - wn][rb + mt * 16 + g]);
            float ps = 0.f;
            #pragma unroll
            for (int t = 0; t < 16; ++t) ps += __expf(20.f * acc[mt][t][g] - csqv[t] - M[mt][g]);
            #pragma unroll
            for (int off = 1; off < 16; off <<= 1) ps += __shfl_xor(ps, off);
            if (cc == 0) red[1][wn][rb + mt * 16 + g] = ps;
        }
    __syncthreads();
    #pragma unroll
    for (int mt = 0; mt < 2; ++mt)
        #pragma unroll
        for (int g = 0; g < 4; ++g)
            I[mt][g] = 1.f / (red[1][0][rb + mt * 16 + g] + red[1][1][rb + mt * 16 + g]);

    // ---- transpose epilogue: 4 passes of 32 rows through lbuf, dense stores ----
    #pragma unroll
    for (int p = 0; p < 4; ++p) {
        if (wm == p) {
            #pragma unroll
            for (int mt = 0; mt < 2; ++mt)
                #pragma unroll
                for (int g = 0; g < 4; ++g) {
                    const int   lr = mt * 16 + q * 4 + g;
                    const float mg = M[mt][g], ig = I[mt][g];
                    #pragma unroll
                    for (int t = 0; t < 16; ++t)
                        sm.lbuf[lr * 516 + wn * 256 + t * 16 + cc] =
                            __expf(20.f * acc[mt][t][g] - csqv[t] - mg) * ig;
                }
        }
        __syncthreads();
        #pragma unroll
        for (int j = 0; j < 8; ++j) {
            const int f    = j * 512 + tid;     // 0..4095 float4 slots
            const int lrow = f >> 7;            // 0..31
            const int c4   = f & 127;
            float4    v    = *(const float4*)&sm.lbuf[lrow * 516 + c4 * 4];
            *(float4*)(out + (size_t)(row0 + p * 32 + lrow) * KC + c4 * 4) = v;
        }
        __syncthreads();
    }
}

extern "C" void kernel_launch(void* const* d_in, const int* in_sizes, int n_in,
                              void* d_out, int out_size, void* d_ws, size_t ws_size,
                              hipStream_t stream) {
    const float* x   = (const float*)d_in[0];
    const float* c   = (const float*)d_in[1];
    float*       out = (float*)d_out;

    unsigned short* bhi   = (unsigned short*)d_ws;                 // 256 KB
    unsigned short* blo   = bhi + (size_t)KCH * CHUNK_USH;         // 256 KB
    float*          csq10 = (float*)(blo + (size_t)KCH * CHUNK_USH);  // 2 KB

    prep_c<<<KC, 64, 0, stream>>>(c, bhi, blo, csq10);
    kmeans_mfma<<<NROWS / BM, 512, 0, stream>>>(x, bhi, blo, csq10, out);
}

// Round 10
// 118.612 us; speedup vs baseline: 1.4469x; 1.4469x over previous
//
#include <hip/hip_runtime.h>

// KMeans soft-assignment via bf16 hi/lo split MFMA (3 passes), fused softmax.
// logits = (2*x.c - ||c||^2)/T, T=0.1; ||x||^2 cancels in softmax.
// R10: B double-buffered via global_load_lds (ZERO staging registers --
// the phantom WRITE in R2/3/4/7/8/9 was register-cap spill writeback, not the
// DMA). 512 thr = 256-reg cap; acc=128 AGPR + ~100 arch now fits. A direct
// from global. One barrier per K-iteration; DMA lands under the MFMA phase.
// x: [32768,256] f32, c: [512,256] f32, out: [32768,512] f32
#define NROWS 32768
#define KC 512
#define DDIM 256
#define BM 128
#define BK 32
#define KCH (DDIM / BK)        // 8 k-chunks
#define CHUNK_USH (KC * BK)    // 16384 ushorts = 32 KB per chunk table

typedef __attribute__((ext_vector_type(8))) short bf16x8;
typedef __attribute__((ext_vector_type(4))) float f32x4;

union U8 { unsigned short u[8]; bf16x8 v; };

__device__ __forceinline__ unsigned short f2bf(float f) {   // RNE f32->bf16
    union { float f; unsigned int u; } a; a.f = f;
    unsigned int r = a.u + 0x7fffu + ((a.u >> 16) & 1u);
    return (unsigned short)(r >> 16);
}
__device__ __forceinline__ float bf2f(unsigned short h) {
    union { unsigned int u; float f; } a; a.u = ((unsigned int)h) << 16;
    return a.f;
}
// async global->LDS, 16B/lane; LDS dst must be wave-uniform base + lane*16
__device__ __forceinline__ void ld16(const void* g, void* l) {
    __builtin_amdgcn_global_load_lds(
        (const __attribute__((address_space(1))) unsigned int*)g,
        (__attribute__((address_space(3))) unsigned int*)l, 16, 0, 0);
}

// ---- prep: c -> chunk-major, LDS-swizzle-baked bf16 hi/lo + csq10 ----
// octet (col n, quad q) at chunk offset (n*4 + (q ^ ((n>>1)&3)))*8 ushorts
__global__ __launch_bounds__(64) void prep_c(const float* __restrict__ c,
                                             unsigned short* __restrict__ bhi,
                                             unsigned short* __restrict__ blo,
                                             float* __restrict__ csq10) {
    const int n = blockIdx.x, lane = threadIdx.x;
    const int d0 = lane * 4;
    float4 v = ((const float4*)(c + (size_t)n * DDIM))[lane];
    float vv[4] = {v.x, v.y, v.z, v.w};
    unsigned short hh[4], ll[4];
    float ssq = 0.f;
    #pragma unroll
    for (int i = 0; i < 4; ++i) {
        ssq += vv[i] * vv[i];
        hh[i] = f2bf(vv[i]);
        ll[i] = f2bf(vv[i] - bf2f(hh[i]));
    }
    #pragma unroll
    for (int off = 32; off; off >>= 1) ssq += __shfl_xor(ssq, off);
    if (lane == 0) csq10[n] = 10.f * ssq;
    const int ks = d0 >> 5;
    const int q  = (d0 >> 3) & 3;
    const int s  = q ^ ((n >> 1) & 3);
    const size_t dst = (size_t)ks * CHUNK_USH + (n * 4 + s) * 8 + (d0 & 7);
    *(ushort4*)(bhi + dst) = make_ushort4(hh[0], hh[1], hh[2], hh[3]);
    *(ushort4*)(blo + dst) = make_ushort4(ll[0], ll[1], ll[2], ll[3]);
}

// ---- main: 256 blocks x 512 threads (8 waves = 4 M-groups x 2 N-halves) ----
union SmemU {
    struct { unsigned short Bh[2][CHUNK_USH], Bl[2][CHUNK_USH]; } k;  // 128 KB
    float lbuf[32 * 516];                                             // 66 KB overlay
};

__global__ __launch_bounds__(512, 2) void kmeans_mfma(
    const float* __restrict__ x, const unsigned short* __restrict__ bhi,
    const unsigned short* __restrict__ blo, const float* __restrict__ csq10,
    float* __restrict__ out) {
    __shared__ __align__(16) SmemU sm;
    __shared__ float red[2][2][BM];   // 2 KB

    const int tid  = threadIdx.x;
    const int w    = tid >> 6, lane = tid & 63;
    const int wm   = w >> 1, wn = w & 1;
    const int cc   = lane & 15, q = lane >> 4;
    const int row0 = blockIdx.x * BM;

    f32x4 acc[2][16];
    #pragma unroll
    for (int mt = 0; mt < 2; ++mt)
        #pragma unroll
        for (int t = 0; t < 16; ++t) acc[mt][t] = (f32x4){0.f, 0.f, 0.f, 0.f};

    // A: lane owns rows (row0 + wm*32 + mt*16 + cc), k-octet q*8 per chunk
    const float* xA0 = x + (size_t)(row0 + wm * 32 + cc) * DDIM + q * 8;
    const float* xA1 = xA0 + (size_t)16 * DDIM;
    // B fragment offset within staged chunk
    const int sF = q ^ ((cc >> 1) & 3);
    const int bF = (4 * cc + sF) * 8;       // + (wn*16+t)*512
    // DMA slots: wave w, j=0..3 -> 1 KB segment (w*4+j)*512 ushorts
    const int dmaOff = (w * 4) * 512;       // ushort offset of this wave's j=0 segment

    // ---- prologue: DMA chunk 0 -> buf 0; load A(0) raw ----
    #pragma unroll
    for (int j = 0; j < 4; ++j) {
        const int o = dmaOff + j * 512;
        ld16(bhi + o + lane * 8, &sm.k.Bh[0][o]);
        ld16(blo + o + lane * 8, &sm.k.Bl[0][o]);
    }
    float4 c00 = *(const float4*)xA0;
    float4 c01 = *(const float4*)(xA0 + 4);
    float4 c10 = *(const float4*)xA1;
    float4 c11 = *(const float4*)(xA1 + 4);
    __syncthreads();   // DMA for buf0 drained

    for (int ks = 0; ks < KCH; ++ks) {
        const int pp = ks & 1;
        float4 n00, n01, n10, n11;
        if (ks < KCH - 1) {
            // issue DMA for next chunk into the other buffer (lands under MFMA)
            const size_t cb = (size_t)(ks + 1) * CHUNK_USH;
            #pragma unroll
            for (int j = 0; j < 4; ++j) {
                const int o = dmaOff + j * 512;
                ld16(bhi + cb + o + lane * 8, &sm.k.Bh[1 - pp][o]);
                ld16(blo + cb + o + lane * 8, &sm.k.Bl[1 - pp][o]);
            }
            const int kn = (ks + 1) * BK;
            n00 = *(const float4*)(xA0 + kn);
            n01 = *(const float4*)(xA0 + kn + 4);
            n10 = *(const float4*)(xA1 + kn);
            n11 = *(const float4*)(xA1 + kn + 4);
        }
        // convert current A to hi/lo fragments
        bf16x8 ah[2], al[2];
        {
            float v0[8] = {c00.x, c00.y, c00.z, c00.w, c01.x, c01.y, c01.z, c01.w};
            float v1[8] = {c10.x, c10.y, c10.z, c10.w, c11.x, c11.y, c11.z, c11.w};
            U8 H0, L0, H1, L1;
            #pragma unroll
            for (int i = 0; i < 8; ++i) {
                H0.u[i] = f2bf(v0[i]); L0.u[i] = f2bf(v0[i] - bf2f(H0.u[i]));
                H1.u[i] = f2bf(v1[i]); L1.u[i] = f2bf(v1[i] - bf2f(H1.u[i]));
            }
            ah[0] = H0.v; al[0] = L0.v; ah[1] = H1.v; al[1] = L1.v;
        }
        // MFMA over staged buffer pp
        #pragma unroll
        for (int t = 0; t < 16; ++t) {
            const int bo = (wn * 16 + t) * 512 + bF;
            bf16x8 bh = *(const bf16x8*)&sm.k.Bh[pp][bo];
            bf16x8 bl = *(const bf16x8*)&sm.k.Bl[pp][bo];
            acc[0][t] = __builtin_amdgcn_mfma_f32_16x16x32_bf16(ah[0], bh, acc[0][t], 0, 0, 0);
            acc[1][t] = __builtin_amdgcn_mfma_f32_16x16x32_bf16(ah[1], bh, acc[1][t], 0, 0, 0);
            acc[0][t] = __builtin_amdgcn_mfma_f32_16x16x32_bf16(ah[0], bl, acc[0][t], 0, 0, 0);
            acc[1][t] = __builtin_amdgcn_mfma_f32_16x16x32_bf16(ah[1], bl, acc[1][t], 0, 0, 0);
            acc[0][t] = __builtin_amdgcn_mfma_f32_16x16x32_bf16(al[0], bh, acc[0][t], 0, 0, 0);
            acc[1][t] = __builtin_amdgcn_mfma_f32_16x16x32_bf16(al[1], bh, acc[1][t], 0, 0, 0);
        }
        c00 = n00; c01 = n01; c10 = n10; c11 = n11;
        __syncthreads();   // next-chunk DMA complete; all waves done with buf pp
    }

    // ---- softmax stats: reduce over t, then cc-lanes, then wn pair via LDS ----
    float csqv[16];
    #pragma unroll
    for (int t = 0; t < 16; ++t) csqv[t] = csq10[wn * 256 + t * 16 + cc];
    const int rb = wm * 32 + q * 4;   // + mt*16 + g
    float M[2][4], I[2][4];
    #pragma unroll
    for (int mt = 0; mt < 2; ++mt)
        #pragma unroll
        for (int g = 0; g < 4; ++g) {
            float pm = -1e30f;
            #pragma unroll
            for (int t = 0; t < 16; ++t) pm = fmaxf(pm, 20.f * acc[mt][t][g] - csqv[t]);
            #pragma unroll
            for (int off = 1; off < 16; off <<= 1) pm = fmaxf(pm, __shfl_xor(pm, off));
            if (cc == 0) red[0][wn][rb + mt * 16 + g] = pm;
            M[mt][g] = pm;
        }
    __syncthreads();
    #pragma unroll
    for (int mt = 0; mt < 2; ++mt)
        #pragma unroll
        for (int g = 0; g < 4; ++g) {
            M[mt][g] = fmaxf(M[mt][g], red[0][1 - wn][rb + mt * 16 + g]);
            float ps = 0.f;
            #pragma unroll
            for (int t = 0; t < 16; ++t) ps += __expf(20.f * acc[mt][t][g] - csqv[t] - M[mt][g]);
            #pragma unroll
            for (int off = 1; off < 16; off <<= 1) ps += __shfl_xor(ps, off);
            if (cc == 0) red[1][wn][rb + mt * 16 + g] = ps;
        }
    __syncthreads();
    #pragma unroll
    for (int mt = 0; mt < 2; ++mt)
        #pragma unroll
        for (int g = 0; g < 4; ++g)
            I[mt][g] = 1.f / (red[1][0][rb + mt * 16 + g] + red[1][1][rb + mt * 16 + g]);

    // ---- transpose epilogue: 4 passes of 32 rows through lbuf, dense stores ----
    #pragma unroll
    for (int p = 0; p < 4; ++p) {
        if (wm == p) {
            #pragma unroll
            for (int mt = 0; mt < 2; ++mt)
                #pragma unroll
                for (int g = 0; g < 4; ++g) {
                    const int   lr = mt * 16 + q * 4 + g;
                    const float mg = M[mt][g], ig = I[mt][g];
                    #pragma unroll
                    for (int t = 0; t < 16; ++t)
                        sm.lbuf[lr * 516 + wn * 256 + t * 16 + cc] =
                            __expf(20.f * acc[mt][t][g] - csqv[t] - mg) * ig;
                }
        }
        __syncthreads();
        #pragma unroll
        for (int j = 0; j < 8; ++j) {
            const int f    = j * 512 + tid;     // 0..4095 float4 slots
            const int lrow = f >> 7;            // 0..31
            const int c4   = f & 127;
            float4    v    = *(const float4*)&sm.lbuf[lrow * 516 + c4 * 4];
            *(float4*)(out + (size_t)(row0 + p * 32 + lrow) * KC + c4 * 4) = v;
        }
        __syncthreads();
    }
}

extern "C" void kernel_launch(void* const* d_in, const int* in_sizes, int n_in,
                              void* d_out, int out_size, void* d_ws, size_t ws_size,
                              hipStream_t stream) {
    const float* x   = (const float*)d_in[0];
    const float* c   = (const float*)d_in[1];
    float*       out = (float*)d_out;

    unsigned short* bhi   = (unsigned short*)d_ws;                 // 256 KB
    unsigned short* blo   = bhi + (size_t)KCH * CHUNK_USH;         // 256 KB
    float*          csq10 = (float*)(blo + (size_t)KCH * CHUNK_USH);  // 2 KB

    prep_c<<<KC, 64, 0, stream>>>(c, bhi, blo, csq10);
    kmeans_mfma<<<NROWS / BM, 512, 0, stream>>>(x, bhi, blo, csq10, out);
}